// Round 2
// baseline (359.389 us; speedup 1.0000x reference)
//
#include <hip/hip_runtime.h>

// VarianceAdaptor: B=16, S=512, C(D_MODEL)=F(FILTER)=512, K=3, T(MAX_FRAMES)=2048
#define B_ 16
#define S_ 512
#define C_ 512
#define T_ 2048

typedef __attribute__((ext_vector_type(8))) short short8;
typedef __attribute__((ext_vector_type(4))) float floatx4;

__device__ __forceinline__ unsigned short f2bf(float x) {
    union { float f; unsigned u; } c; c.f = x;
    unsigned r = (c.u + 0x7fffu + ((c.u >> 16) & 1u)) >> 16;
    return (unsigned short)r;
}

// async global->LDS, 16B per lane; lds dest = wave-uniform base + lane*16
__device__ __forceinline__ void gld_lds16(void* l, const void* g) {
    __builtin_amdgcn_global_load_lds(
        (const __attribute__((address_space(1))) void*)g,
        (__attribute__((address_space(3))) void*)l, 16, 0, 0);
}

// ---------------------------------------------------------------------------
// Fused prep: pack 6 conv weights (F,C,3)fp32 -> (3,F,C)bf16 [blocks 0..6143],
// cast H->bf16 [6144..10239], zero zrow [10240..10241], length-regulator
// rowidx [10242..10257], fill preds with final bias [10258..10545].
__global__ void prep_kernel(const float* __restrict__ w0, const float* __restrict__ w1,
                            const float* __restrict__ w2, const float* __restrict__ w3,
                            const float* __restrict__ w4, const float* __restrict__ w5,
                            unsigned short* __restrict__ wpack,
                            const float* __restrict__ H, unsigned short* __restrict__ Hbf,
                            unsigned short* __restrict__ zrow,
                            const int* __restrict__ Dgt, int* __restrict__ ridx,
                            float* __restrict__ Dp, float* __restrict__ Pp, float* __restrict__ Ep,
                            const float* __restrict__ dbl, const float* __restrict__ pbl,
                            const float* __restrict__ ebl) {
    __shared__ int cs[S_];
    __shared__ int ps[256];
    int blk = blockIdx.x;
    int tid = threadIdx.x;
    if (blk < 6144) {                      // weight pack: 6 x 1024 blocks
        int which = blk >> 10;
        const float* w = which == 0 ? w0 : which == 1 ? w1 : which == 2 ? w2
                       : which == 3 ? w3 : which == 4 ? w4 : w5;
        unsigned short* wp = wpack + (long)which * 786432;
        int i = (blk & 1023) * 256 + tid;   // i over F*C = 262144
        const float* s = w + (long)i * 3;
        wp[i]          = f2bf(s[0]);
        wp[i + 262144] = f2bf(s[1]);
        wp[i + 524288] = f2bf(s[2]);
    } else if (blk < 10240) {              // H fp32 -> bf16: 4096 blocks x 4 elems
        int i = (blk - 6144) * 256 + tid;
        float4 v = *(const float4*)(H + (long)i * 4);
        ushort4 o;
        o.x = f2bf(v.x); o.y = f2bf(v.y); o.z = f2bf(v.z); o.w = f2bf(v.w);
        *(ushort4*)(Hbf + (long)i * 4) = o;
    } else if (blk < 10242) {              // zrow: 2 blocks
        zrow[(blk - 10240) * 256 + tid] = 0;
    } else if (blk < 10258) {              // expand rowidx: 16 blocks (one/batch)
        int b = blk - 10242;
        int t2 = tid * 2;
        int d0 = Dgt[b * S_ + t2], d1 = Dgt[b * S_ + t2 + 1];
        int a0 = d0 < 0 ? 0 : d0, a1 = d1 < 0 ? 0 : d1;
        ps[tid] = a0 + a1;
        __syncthreads();
        for (int off = 1; off < 256; off <<= 1) {
            int v = (tid >= off) ? ps[tid - off] : 0;
            __syncthreads();
            ps[tid] += v;
            __syncthreads();
        }
        int incl = ps[tid];
        cs[t2] = incl - a1;
        cs[t2 + 1] = incl;
        __syncthreads();
        int total = cs[S_ - 1];
        int limit = total < T_ ? total : T_;
        for (int t = tid; t < T_; t += 256) {
            int lo = 0, hi = S_;
            while (lo < hi) { int mid = (lo + hi) >> 1; if (cs[mid] <= t) lo = mid + 1; else hi = mid; }
            if (lo > S_ - 1) lo = S_ - 1;
            ridx[b * T_ + t] = (t < limit) ? lo : -1;
        }
    } else {                               // fill preds: 288 blocks
        int i = (blk - 10258) * 256 + tid;
        if (i < 8192) Dp[i] = dbl[0];
        else if (i < 40960) Pp[i - 8192] = pbl[0];
        else Ep[i - 40960] = ebl[0];
    }
}

// ---------------------------------------------------------------------------
// Mega kernel: up to three tap-fused bf16-MFMA conv-GEMM jobs (block ranges
// [0,e0), [e0,e1), [e1,e2)) plus optional adapt blocks [e2, grid). Conv body
// identical to R4 (XOR bank-swizzle, 0 conflicts, ~890 TF plateau).
//   D[f, p] = sum_{tap, c} W[tap][f][c] * X[row(p + tap - 1)][c]
// mode 0: dst(bf16)[p*C + f] = relu(D + bias[f])
// mode 1: atomicAdd(dst(f32)[p], sum_f relu(D + bias[f]) * wl[f])
// Adapt blocks: H_adapted = gather(H) + P_gt*pw + pb + E_gt*ew + eb (fp32).
//
// Occupancy note: LDS padded to 41.5 KB so blocks/CU = floor(160/41.5) = 3
// (768 resident blocks). Conv grids are 2304 = 3 x 768 -> exact round packing,
// removing the 256-block tail round that ran the machine at ~25%.
struct ConvJob {
    const unsigned short* X;    // bf16 rows [B << Bshift][C]
    const int* ridx;            // per (b,t) row-in-batch, or nullptr = identity
    int Lshift;                 // log2 positions per batch
    int Bshift;                 // log2 rows per batch of X
    const unsigned short* wp;   // [3][512][512] bf16
    const float* bias;
    const float* wl;
    void* dst;
    int nxshift;                // log2 of x-tiles (position tiles)
};

__global__ __launch_bounds__(256, 3) void mega_kernel(
    ConvJob j0, ConvJob j1, ConvJob j2, int e0, int e1, int e2, int mode, int aoff,
    const unsigned short* __restrict__ zrow,
    const float* __restrict__ H, const int* __restrict__ aridx,
    const float* __restrict__ Pgt, const float* __restrict__ Egt,
    const float* __restrict__ pw, const float* __restrict__ pb,
    const float* __restrict__ ew, const float* __restrict__ eb,
    float* __restrict__ aout)
{
    __shared__ unsigned short Wt[3 * 128 * 32];        // 24 KB  [tap][frow][k32]
    __shared__ unsigned short Xt[136 * 32 + 4096];     // 8.5 KB used + 8 KB occupancy pad
    const int bx = blockIdx.x;
    const int tid = threadIdx.x;

    if (bx >= e2) {
        // ---- adapt path: aoff selects which half of the 2048-block range ----
        int ab = bx - e2 + aoff;
#pragma unroll
        for (int it = 0; it < 8; ++it) {
            int i = ab * 256 + tid + it * 524288;
            int f4 = i & 127;
            int p  = i >> 7;
            int b  = p >> 11;
            int r  = aridx[p];
            float pg = Pgt[p], eg = Egt[p];
            int f = f4 << 2;
            float4 pwv = *(const float4*)(pw + f);
            float4 pbv = *(const float4*)(pb + f);
            float4 ewv = *(const float4*)(ew + f);
            float4 ebv = *(const float4*)(eb + f);
            float4 h = make_float4(0.f, 0.f, 0.f, 0.f);
            if (r >= 0) h = *(const float4*)(H + ((long)b * S_ + r) * C_ + f);
            float4 o;
            o.x = h.x + pg * pwv.x + pbv.x + eg * ewv.x + ebv.x;
            o.y = h.y + pg * pwv.y + pbv.y + eg * ewv.y + ebv.y;
            o.z = h.z + pg * pwv.z + pbv.z + eg * ewv.z + ebv.z;
            o.w = h.w + pg * pwv.w + pbv.w + eg * ewv.w + ebv.w;
            *(float4*)(aout + (long)p * C_ + f) = o;
        }
        return;
    }

    ConvJob j;
    int local;
    if (bx < e0)      { j = j0; local = bx; }
    else if (bx < e1) { j = j1; local = bx - e0; }
    else              { j = j2; local = bx - e1; }
    const int m0 = (local >> j.nxshift) * 128;
    const int n0 = (local & ((1 << j.nxshift) - 1)) * 128;
    const int L = 1 << j.Lshift;
    const int b = n0 >> j.Lshift;
    const int t0 = n0 & (L - 1);

    floatx4 acc[4][4];
#pragma unroll
    for (int i = 0; i < 4; ++i)
#pragma unroll
        for (int jj = 0; jj < 4; ++jj) acc[i][jj] = (floatx4){0.f, 0.f, 0.f, 0.f};

    // --- staging pointers (chunk idx -> 16B), source-seg XOR swizzle ---
    const unsigned short* wptr[6];
#pragma unroll
    for (int q = 0; q < 6; ++q) {
        int idx = tid + q * 256;
        int tap = idx >> 9, rem = idx & 511;
        int row = rem >> 2;
        int sw = (rem & 3) ^ ((row >> 1) & 3);
        wptr[q] = j.wp + (long)tap * (C_ * C_) + (long)(m0 + row) * C_ + sw * 8;
    }
    auto xrow = [&](int rho) -> const unsigned short* {
        int t = t0 - 1 + rho;
        if (t < 0 || t >= L) return zrow;
        int r = j.ridx ? j.ridx[(b << j.Lshift) + t] : t;
        if (r < 0) return zrow;
        return j.X + ((long)(b << j.Bshift) + r) * C_;
    };
    const int xs = tid & 3;
    const int rho0 = tid >> 2, rho1 = 64 + (tid >> 2), rho2 = 128 + (tid >> 2);
    const unsigned short* xptr0 = xrow(rho0) + (xs ^ ((rho0 >> 1) & 3)) * 8;
    const unsigned short* xptr1 = xrow(rho1) + (xs ^ ((rho1 >> 1) & 3)) * 8;
    const unsigned short* xptr2 = (tid < 8) ? (xrow(rho2) + (xs ^ ((rho2 >> 1) & 3)) * 8) : zrow;

    char* wbase = (char*)Wt + (tid >> 6) * 1024;   // wave-uniform LDS bases
    char* xbase = (char*)Xt + (tid >> 6) * 1024;

    // --- compute-side lane mapping (wave grid 2(m) x 2(n)) ---
    const int lane = tid & 63;
    const int q = lane >> 4, lr = lane & 15;
    const int wm = (tid >> 6) & 1, wn = tid >> 7;
    const int qsW = (q ^ ((lr >> 1) & 3)) * 8;
    int qsX[3];
#pragma unroll
    for (int tap = 0; tap < 3; ++tap)
        qsX[tap] = (q ^ (((lr + tap) >> 1) & 3)) * 8;

    for (int c0 = 0; c0 < C_; c0 += 32) {
        __syncthreads();
#pragma unroll
        for (int qq = 0; qq < 6; ++qq)
            gld_lds16(wbase + qq * 4096, wptr[qq] + c0);
        gld_lds16(xbase, xptr0 + c0);
        gld_lds16(xbase + 4096, xptr1 + c0);
        if (tid < 8)
            gld_lds16((char*)Xt + 8192, xptr2 + c0);
        __syncthreads();
#pragma unroll
        for (int tap = 0; tap < 3; ++tap) {
            const unsigned short* Wl = Wt + ((tap * 128) + wm * 64 + lr) * 32 + qsW;
            const unsigned short* Xl = Xt + (wn * 64 + lr + tap) * 32 + qsX[tap];
            short8 a[4], bf[4];
#pragma unroll
            for (int i = 0; i < 4; ++i) {
                a[i]  = *(const short8*)(Wl + i * 16 * 32);
                bf[i] = *(const short8*)(Xl + i * 16 * 32);
            }
#pragma unroll
            for (int i = 0; i < 4; ++i)
#pragma unroll
                for (int jj = 0; jj < 4; ++jj)
                    acc[i][jj] = __builtin_amdgcn_mfma_f32_16x16x32_bf16(
                        a[i], bf[jj], acc[i][jj], 0, 0, 0);
        }
    }

    // D lane mapping: col = lane&15 = p, row = q*4 + reg = f
    const int fbase = m0 + wm * 64 + q * 4;
    const int pbase = n0 + wn * 64 + lr;
    if (mode == 0) {
        unsigned short* dst = (unsigned short*)j.dst;
#pragma unroll
        for (int i = 0; i < 4; ++i) {
            int f = fbase + i * 16;
            float4 bv = *(const float4*)(j.bias + f);
#pragma unroll
            for (int jj = 0; jj < 4; ++jj) {
                int p = pbase + jj * 16;
                ushort4 o;
                o.x = f2bf(fmaxf(acc[i][jj][0] + bv.x, 0.f));
                o.y = f2bf(fmaxf(acc[i][jj][1] + bv.y, 0.f));
                o.z = f2bf(fmaxf(acc[i][jj][2] + bv.z, 0.f));
                o.w = f2bf(fmaxf(acc[i][jj][3] + bv.w, 0.f));
                *(ushort4*)(dst + (long)p * C_ + f) = o;
            }
        }
    } else {
        float* dst = (float*)j.dst;
#pragma unroll
        for (int jj = 0; jj < 4; ++jj) {
            float s = 0.f;
#pragma unroll
            for (int i = 0; i < 4; ++i) {
                int f = fbase + i * 16;
                float4 bv = *(const float4*)(j.bias + f);
                float4 wv = *(const float4*)(j.wl + f);
                s += fmaxf(acc[i][jj][0] + bv.x, 0.f) * wv.x;
                s += fmaxf(acc[i][jj][1] + bv.y, 0.f) * wv.y;
                s += fmaxf(acc[i][jj][2] + bv.z, 0.f) * wv.z;
                s += fmaxf(acc[i][jj][3] + bv.w, 0.f) * wv.w;
            }
            s += __shfl_xor(s, 16, 64);
            s += __shfl_xor(s, 32, 64);
            if (lane < 16) atomicAdd(dst + pbase + jj * 16, s);
        }
    }
}

// ---------------------------------------------------------------------------
extern "C" void kernel_launch(void* const* d_in, const int* in_sizes, int n_in,
                              void* d_out, int out_size, void* d_ws, size_t ws_size,
                              hipStream_t stream) {
    const float* H    = (const float*)d_in[0];
    const int*   Dgt  = (const int*)d_in[1];
    const float* Pgt  = (const float*)d_in[2];
    const float* Egt  = (const float*)d_in[3];
    const float* dp_w1 = (const float*)d_in[4];
    const float* dp_b1 = (const float*)d_in[5];
    const float* dp_w2 = (const float*)d_in[6];
    const float* dp_b2 = (const float*)d_in[7];
    const float* dp_wl = (const float*)d_in[8];
    const float* dp_bl = (const float*)d_in[9];
    const float* pp_w1 = (const float*)d_in[10];
    const float* pp_b1 = (const float*)d_in[11];
    const float* pp_w2 = (const float*)d_in[12];
    const float* pp_b2 = (const float*)d_in[13];
    const float* pp_wl = (const float*)d_in[14];
    const float* pp_bl = (const float*)d_in[15];
    const float* ep_w1 = (const float*)d_in[16];
    const float* ep_b1 = (const float*)d_in[17];
    const float* ep_w2 = (const float*)d_in[18];
    const float* ep_b2 = (const float*)d_in[19];
    const float* ep_wl = (const float*)d_in[20];
    const float* ep_bl = (const float*)d_in[21];
    const float* pitch_w  = (const float*)d_in[22];
    const float* pitch_b  = (const float*)d_in[23];
    const float* energy_w = (const float*)d_in[24];
    const float* energy_b = (const float*)d_in[25];

    float* out     = (float*)d_out;
    float* H_adapt = out;                       // 16*2048*512 = 16,777,216
    float* D_pred  = out + 16777216;            // 16*512 = 8192
    float* P_pred  = out + 16785408;            // 16*2048 = 32768
    float* E_pred  = out + 16818176;            // 16*2048 = 32768

    // ws_size is call-invariant, so this layout choice is graph-stable.
    const bool par = ws_size >= 94000000ull;    // parallel-ep plan needs ~89.1 MiB

    char* ws = (char*)d_ws;
    size_t off = 0;
    unsigned short* wpack = (unsigned short*)(ws + off); off += 6UL * 786432UL * 2UL;  // 9.4 MB
    unsigned short* Hbf   = (unsigned short*)(ws + off); off += 4194304UL * 2UL;       // 8 MB
    unsigned short* h1a   = (unsigned short*)(ws + off); off += 16777216UL * 2UL;      // 33.5 MB (pp)
    unsigned short* h1b   = par ? (unsigned short*)(ws + off) : h1a;                   // ep
    if (par) off += 16777216UL * 2UL;
    unsigned short* h1dp  = (unsigned short*)(ws + off); off += 4194304UL * 2UL;       // 8 MB
    unsigned short* zrow  = (unsigned short*)(ws + off); off += 512UL * 2UL;
    off = (off + 255) & ~(size_t)255;
    int* ridx_exp = (int*)(ws + off); off += (size_t)B_ * T_ * 4;

    hipLaunchKernelGGL(prep_kernel, dim3(10546), dim3(256), 0, stream,
                       dp_w1, dp_w2, pp_w1, pp_w2, ep_w1, ep_w2, wpack, H, Hbf, zrow,
                       Dgt, ridx_exp, D_pred, P_pred, E_pred, dp_bl, pp_bl, ep_bl);

    ConvJob j_pp1 = { Hbf,  ridx_exp, 11,  9, wpack + 2UL * 786432, pp_b1, nullptr, h1a,    8 };
    ConvJob j_ep1 = { Hbf,  ridx_exp, 11,  9, wpack + 4UL * 786432, ep_b1, nullptr, h1b,    8 };
    ConvJob j_dp1 = { Hbf,  nullptr,   9,  9, wpack + 0UL * 786432, dp_b1, nullptr, h1dp,   6 };
    ConvJob j_pp2 = { h1a,  nullptr,  11, 11, wpack + 3UL * 786432, pp_b2, pp_wl,  P_pred, 8 };
    ConvJob j_ep2 = { h1b,  nullptr,  11, 11, wpack + 5UL * 786432, ep_b2, ep_wl,  E_pred, 8 };
    ConvJob j_dp2 = { h1dp, nullptr,   9,  9, wpack + 1UL * 786432, dp_b2, dp_wl,  D_pred, 6 };

    if (par) {
        // conv1 (2304 = 3 rounds at 3 blk/CU) + first half of adapt (1024)
        hipLaunchKernelGGL(mega_kernel, dim3(2304 + 1024), dim3(256), 0, stream,
                           j_pp1, j_ep1, j_dp1, 1024, 2048, 2304, 0, 0, zrow,
                           H, ridx_exp, Pgt, Egt, pitch_w, pitch_b, energy_w, energy_b, H_adapt);
        // conv2 + fused final linear (2304 = 3 rounds) + second half of adapt
        hipLaunchKernelGGL(mega_kernel, dim3(2304 + 1024), dim3(256), 0, stream,
                           j_pp2, j_ep2, j_dp2, 1024, 2048, 2304, 1, 1024, zrow,
                           H, ridx_exp, Pgt, Egt, pitch_w, pitch_b, energy_w, energy_b, H_adapt);
    } else {
        // serialized ep (h1b aliases h1a): pp+dp first (+all adapt), then ep
        hipLaunchKernelGGL(mega_kernel, dim3(1280 + 2048), dim3(256), 0, stream,
                           j_pp1, j_dp1, j_dp1, 1024, 1280, 1280, 0, 0, zrow,
                           H, ridx_exp, Pgt, Egt, pitch_w, pitch_b, energy_w, energy_b, H_adapt);
        hipLaunchKernelGGL(mega_kernel, dim3(1280), dim3(256), 0, stream,
                           j_pp2, j_dp2, j_dp2, 1024, 1280, 1280, 1, 0, zrow,
                           H, ridx_exp, Pgt, Egt, pitch_w, pitch_b, energy_w, energy_b, H_adapt);
        hipLaunchKernelGGL(mega_kernel, dim3(1024), dim3(256), 0, stream,
                           j_ep1, j_ep1, j_ep1, 1024, 1024, 1024, 0, 0, zrow,
                           H, ridx_exp, Pgt, Egt, pitch_w, pitch_b, energy_w, energy_b, H_adapt);
        hipLaunchKernelGGL(mega_kernel, dim3(1024), dim3(256), 0, stream,
                           j_ep2, j_ep2, j_ep2, 1024, 1024, 1024, 1, 0, zrow,
                           H, ridx_exp, Pgt, Egt, pitch_w, pitch_b, energy_w, energy_b, H_adapt);
    }
}